// Round 6
// baseline (1445.326 us; speedup 1.0000x reference)
//
#include <hip/hip_runtime.h>
#include <hip/hip_bf16.h>
#include <math.h>

// ---------------------------------------------------------------------------
// GCN pipeline, super-bucket formulation v2 (resubmit — round-5 bench never ran):
//   - edges binned by destination into NB buckets of BN=512 nodes
//     (LDS-staged coalesced binning, packed u32 = row | localcol<<18)
//   - per-bucket counting sort by source region (8 groups) for L2 locality
//   - layer kernels: one block per (bucket, edge-slice); ALL features
//     accumulated in one block (4 threads/edge read one 64B record once),
//     feature-major LDS acc with stride 516 (bank-spread); partials dumped,
//     summed in streaming finalize kernels fused with the tiny GEMMs.
//   - only global f32 atomics: mean-pool into 132KB L2-resident table.
// ---------------------------------------------------------------------------

#define TPB 256
#define BSH 9
#define BN 512             // destination nodes per bucket
#define NBMAX 512
#define EPT 16             // edges per thread in k_bin
#define CAPL 16            // staging slots per bucket per chunk
#define S1 4               // edge slices, layer 1
#define S2 2               // edge slices, layer 2
#define STR 516            // LDS accumulator stride (bank spread)
#define ROWM 0x3FFFF

__device__ __forceinline__ void atomAddF(float* p, float v) {
    unsafeAtomicAdd(p, v);   // hardware global_atomic_add_f32
}

// --- K0: cursor init: cur[b] = b*CAPB ---
__global__ void k_curinit(int* __restrict__ cur, int NB, int CAPB) {
    int t = threadIdx.x;
    for (int b = t; b < NB; b += TPB) cur[b] = b * CAPB;
}

// --- K1: LDS-staged binning. Each block owns one 4096-edge chunk. ---
__global__ void k_bin(const int* __restrict__ row, const int* __restrict__ col, int E,
                      int NB, int* __restrict__ cur, unsigned* __restrict__ blist) {
    __shared__ unsigned lh[NBMAX * CAPL];
    __shared__ int lcnt[NBMAX];
    __shared__ int gb[NBMAX];
    const int t = threadIdx.x;
    for (int j = t; j < NBMAX; j += TPB) lcnt[j] = 0;
    __syncthreads();
    const int base = blockIdx.x * (TPB * EPT);
#pragma unroll 4
    for (int j = 0; j < EPT; ++j) {
        int e = base + j * TPB + t;
        if (e < E) {
            int c = col[e];
            int b = c >> BSH;
            unsigned val = (unsigned)row[e] | ((unsigned)(c & (BN - 1)) << 18);
            int pos = atomicAdd(&lcnt[b], 1);
            if (pos < CAPL) lh[b * CAPL + pos] = val;
            else { int gp = atomicAdd(&cur[b], 1); blist[gp] = val; }  // rare spill
        }
    }
    __syncthreads();
    for (int b = t; b < NB; b += TPB) {
        int c = min(lcnt[b], CAPL);
        gb[b] = c ? atomicAdd(&cur[b], c) : 0;
    }
    __syncthreads();
    for (int slot = t; slot < NB * CAPL; slot += TPB) {
        int b = slot >> 4;               // CAPL = 16
        int p = slot & (CAPL - 1);
        if (p < min(lcnt[b], CAPL)) blist[gb[b] + p] = lh[slot];
    }
}

// --- K2: per-bucket counting sort by source group (r>>15), 8 groups ---
__global__ void k_srcsort(const unsigned* __restrict__ bl, const int* __restrict__ bend,
                          int CAPB, unsigned* __restrict__ bl2) {
    __shared__ int cnt[8], cur8[8];
    const int t = threadIdx.x, b = blockIdx.x;
    if (t < 8) cnt[t] = 0;
    __syncthreads();
    const int lo = b * CAPB, hi = bend[b];
    for (int k = lo + t; k < hi; k += TPB)
        atomicAdd(&cnt[(bl[k] & ROWM) >> 15], 1);
    __syncthreads();
    if (t == 0) {
        int s = 0;
        for (int g = 0; g < 8; ++g) { cur8[g] = s; s += cnt[g]; }
    }
    __syncthreads();
    for (int k = lo + t; k < hi; k += TPB) {
        unsigned pv = bl[k];
        int g = (pv & ROWM) >> 15;
        int pos = atomicAdd(&cur8[g], 1);
        bl2[lo + pos] = pv;
    }
}

// --- K3: per-bucket degree hist -> dinv, y1 = x*dinv (padded float4) ---
__global__ void k_deginit(const unsigned* __restrict__ bl, const int* __restrict__ bend,
                          int CAPB, const float* __restrict__ x,
                          float* __restrict__ dinv, float4* __restrict__ y1, int N) {
    __shared__ int hist[BN];
    const int t = threadIdx.x, b = blockIdx.x;
    for (int j = t; j < BN; j += TPB) hist[j] = 0;
    __syncthreads();
    const int lo = b * CAPB, hi = bend[b];
    for (int k = lo + t; k < hi; k += TPB)
        atomicAdd(&hist[bl[k] >> 18], 1);
    __syncthreads();
    for (int j = t; j < BN; j += TPB) {
        int i = b * BN + j;
        if (i < N) {
            float d = rsqrtf(1.0f + (float)hist[j]);
            dinv[i] = d;
            float4 v;
            v.x = x[3 * (size_t)i + 0] * d;
            v.y = x[3 * (size_t)i + 1] * d;
            v.z = x[3 * (size_t)i + 2] * d;
            v.w = 0.0f;
            y1[i] = v;
        }
    }
}

// --- K4: layer1 partial accumulate (bucket x slice), 3 feats, LDS acc ---
__global__ void k_layer1(const unsigned* __restrict__ bl, const int* __restrict__ bend,
                         int CAPB, const float4* __restrict__ y1,
                         float* __restrict__ p1) {
    __shared__ float acc[3 * STR];
    const int t = threadIdx.x;
    const int b = blockIdx.x >> 2;        // S1 = 4
    const int sl = blockIdx.x & 3;
    for (int j = t; j < 3 * STR; j += TPB) acc[j] = 0.0f;
    __syncthreads();
    const int lo0 = b * CAPB, n = bend[b] - lo0;
    const int len = (n + S1 - 1) / S1;
    int lo = lo0 + sl * len;
    int hi = lo + len; { int e2 = lo0 + n; if (hi > e2) hi = e2; }
#pragma unroll 2
    for (int k = lo + t; k < hi; k += TPB) {
        unsigned pv = bl[k];
        int r = pv & ROWM, lc = pv >> 18;
        float4 v = y1[r];
        atomicAdd(&acc[lc],           v.x);
        atomicAdd(&acc[STR + lc],     v.y);
        atomicAdd(&acc[2 * STR + lc], v.z);
    }
    __syncthreads();
    float* out = p1 + (size_t)(b * S1 + sl) * (3 * BN);
    for (int j = t; j < 3 * BN; j += TPB) {
        int f = j >> BSH, lc = j & (BN - 1);
        out[j] = acc[f * STR + lc];
    }
}

// --- K5: finalize layer1: partials + self, scale, 3x16 GEMM, relu, prescale ---
__global__ void k_fin1(const float* __restrict__ p1, const float4* __restrict__ y1,
                       const float* __restrict__ dinv,
                       const float* __restrict__ W1, const float* __restrict__ b1,
                       float* __restrict__ y2, int N) {
    __shared__ float sW[48];
    __shared__ float sb[16];
    if (threadIdx.x < 48) sW[threadIdx.x] = W1[threadIdx.x];
    if (threadIdx.x < 16) sb[threadIdx.x] = b1[threadIdx.x];
    __syncthreads();
    int i = blockIdx.x * TPB + threadIdx.x;
    if (i >= N) return;
    const int b = i >> BSH, li = i & (BN - 1);
    float4 a = y1[i];                    // self-loop term
    float ax = a.x, ay = a.y, az = a.z;
#pragma unroll
    for (int sl = 0; sl < S1; ++sl) {
        const float* q = p1 + (size_t)(b * S1 + sl) * (3 * BN);
        ax += q[li]; ay += q[BN + li]; az += q[2 * BN + li];
    }
    const float d = dinv[i];
    ax *= d; ay *= d; az *= d;
    float h[16];
#pragma unroll
    for (int f = 0; f < 16; ++f) {
        float t = sb[f] + ax * sW[f] + ay * sW[16 + f] + az * sW[32 + f];
        h[f] = fmaxf(t, 0.0f) * d;       // relu then pre-scale for next layer
    }
    float4* py = (float4*)(y2 + (size_t)i * 16);
#pragma unroll
    for (int q = 0; q < 4; ++q)
        py[q] = make_float4(h[4*q], h[4*q+1], h[4*q+2], h[4*q+3]);
}

// --- K6: layer2 partial accumulate (bucket x slice), ALL 16 feats,
//         4 threads/edge read one 64B record once ---
__global__ void k_layer2(const unsigned* __restrict__ bl, const int* __restrict__ bend,
                         int CAPB, const float* __restrict__ y2,
                         float* __restrict__ p2) {
    __shared__ float acc[16 * STR];      // 33 KB
    const int t = threadIdx.x;
    const int b = blockIdx.x >> 1;       // S2 = 2
    const int sl = blockIdx.x & 1;
    for (int j = t; j < 16 * STR; j += TPB) acc[j] = 0.0f;
    __syncthreads();
    const int lo0 = b * CAPB, n = bend[b] - lo0;
    const int len = (n + S2 - 1) / S2;
    int lo = lo0 + sl * len;
    int hi = lo + len; { int e2 = lo0 + n; if (hi > e2) hi = e2; }
    const int q = t & 3;
#pragma unroll 2
    for (int k = lo + (t >> 2); k < hi; k += TPB / 4) {
        unsigned pv = bl[k];             // 4 lanes broadcast-read same word
        int r = pv & ROWM, lc = pv >> 18;
        float4 v = ((const float4*)(y2 + (size_t)r * 16))[q];
        float* a = &acc[(q * 4) * STR + lc];
        atomicAdd(a,           v.x);
        atomicAdd(a + STR,     v.y);
        atomicAdd(a + 2 * STR, v.z);
        atomicAdd(a + 3 * STR, v.w);
    }
    __syncthreads();
    float* out = p2 + (size_t)(b * S2 + sl) * (16 * BN);
    for (int j = t; j < 16 * BN; j += TPB) {
        int f = j >> BSH, lc = j & (BN - 1);
        out[j] = acc[f * STR + lc];
    }
}

// --- K7: finalize layer2: partials + self, scale, 16x32 GEMM, relu, pool ---
__global__ void k_fin2pool(const float* __restrict__ p2, const float* __restrict__ y2,
                           const float* __restrict__ dinv,
                           const float* __restrict__ W2, const float* __restrict__ b2,
                           const int* __restrict__ batch,
                           float* __restrict__ gsum, float* __restrict__ gcnt, int N) {
    __shared__ float sW[512];
    __shared__ float sb[32];
    for (int j = threadIdx.x; j < 512; j += TPB) sW[j] = W2[j];
    if (threadIdx.x < 32) sb[threadIdx.x] = b2[threadIdx.x];
    __syncthreads();
    int i = blockIdx.x * TPB + threadIdx.x;
    if (i >= N) return;
    const int b = i >> BSH, li = i & (BN - 1);
    float v[16];
    const float4* self = (const float4*)(y2 + (size_t)i * 16);
#pragma unroll
    for (int fq = 0; fq < 4; ++fq) {
        float4 sv = self[fq];
        v[fq*4+0] = sv.x; v[fq*4+1] = sv.y; v[fq*4+2] = sv.z; v[fq*4+3] = sv.w;
    }
#pragma unroll
    for (int sl = 0; sl < S2; ++sl) {
        const float* q = p2 + (size_t)(b * S2 + sl) * (16 * BN);
#pragma unroll
        for (int f = 0; f < 16; ++f) v[f] += q[f * BN + li];
    }
    const float d = dinv[i];
#pragma unroll
    for (int c = 0; c < 16; ++c) v[c] *= d;
    const int g = batch[i];
    float* gs = gsum + (size_t)g * 32;
#pragma unroll
    for (int f = 0; f < 32; ++f) {
        float t = sb[f];
#pragma unroll
        for (int c = 0; c < 16; ++c) t += v[c] * sW[c * 32 + f];
        atomAddF(&gs[f], fmaxf(t, 0.0f));
    }
    atomAddF(&gcnt[g], 1.0f);
}

// --- K8: mean -> FC -> log_softmax ---
__global__ void k_head(const float* __restrict__ gsum, const float* __restrict__ gcnt,
                       const float* __restrict__ Wfc, const float* __restrict__ bfc,
                       float* __restrict__ out, int G) {
    int g = blockIdx.x * TPB + threadIdx.x;
    if (g < G) {
        float inv = 1.0f / fmaxf(gcnt[g], 1.0f);
        float l0 = bfc[0], l1 = bfc[1];
        const float* gs = gsum + (size_t)g * 32;
#pragma unroll
        for (int j = 0; j < 32; ++j) {
            float m = gs[j] * inv;
            l0 += m * Wfc[j * 2 + 0];
            l1 += m * Wfc[j * 2 + 1];
        }
        float mx = fmaxf(l0, l1);
        float lse = mx + logf(expf(l0 - mx) + expf(l1 - mx));
        out[g * 2 + 0] = l0 - lse;
        out[g * 2 + 1] = l1 - lse;
    }
}

extern "C" void kernel_launch(void* const* d_in, const int* in_sizes, int n_in,
                              void* d_out, int out_size, void* d_ws, size_t ws_size,
                              hipStream_t stream) {
    const float* x     = (const float*)d_in[0];
    const int*   edge  = (const int*)  d_in[1];
    const int*   batch = (const int*)  d_in[2];
    const float* W1    = (const float*)d_in[3];
    const float* b1    = (const float*)d_in[4];
    const float* W2    = (const float*)d_in[5];
    const float* b2    = (const float*)d_in[6];
    const float* Wfc   = (const float*)d_in[7];
    const float* bfc   = (const float*)d_in[8];

    const int N = in_sizes[0] / 3;
    const int E = in_sizes[1] / 2;
    const int G = out_size / 2;
    const int NB = (N + BN - 1) >> BSH;              // 391 for N=200000
    const int CAPB = (E + NB - 1) / NB + 2048;       // mean + ~16 sigma slack
    const int* row = edge;
    const int* col = edge + E;

    // workspace partition (256B aligned); pbuf aliases blistA (dead after sort)
    char* base = (char*)d_ws;
    size_t o = 0;
    auto take = [&](size_t bytes) { char* r = base + o; o += (bytes + 255) & ~(size_t)255; return r; };
    int*      cur    = (int*)     take((size_t)NB * 4);
    unsigned* blistA = (unsigned*)take((size_t)NB * CAPB * 4);
    unsigned* blistB = (unsigned*)take((size_t)NB * CAPB * 4);
    float*    dinv   = (float*)   take((size_t)N * 4);
    float4*   y1     = (float4*)  take((size_t)N * 16);
    float*    y2     = (float*)   take((size_t)N * 64);
    float*    gsum   = (float*)   take((size_t)G * 33 * 4);
    float*    gcnt   = gsum + (size_t)G * 32;
    float*    pbuf   = (float*)blistA;   // S2*NB*16*BN*4 = 25.6MB <= 28.9MB

    hipMemsetAsync(gsum, 0, (size_t)G * 33 * 4, stream);

    const int gBin = (E + TPB * EPT - 1) / (TPB * EPT);
    const int gN   = (N + TPB - 1) / TPB;
    const int gG   = (G + TPB - 1) / TPB;

    k_curinit <<<1, TPB, 0, stream>>>(cur, NB, CAPB);
    k_bin     <<<gBin, TPB, 0, stream>>>(row, col, E, NB, cur, blistA);
    k_srcsort <<<NB, TPB, 0, stream>>>(blistA, cur, CAPB, blistB);
    k_deginit <<<NB, TPB, 0, stream>>>(blistB, cur, CAPB, x, dinv, y1, N);
    k_layer1  <<<NB * S1, TPB, 0, stream>>>(blistB, cur, CAPB, y1, pbuf);
    k_fin1    <<<gN, TPB, 0, stream>>>(pbuf, y1, dinv, W1, b1, y2, N);
    k_layer2  <<<NB * S2, TPB, 0, stream>>>(blistB, cur, CAPB, y2, pbuf);
    k_fin2pool<<<gN, TPB, 0, stream>>>(pbuf, y2, dinv, W2, b2, batch, gsum, gcnt, N);
    k_head    <<<gG, TPB, 0, stream>>>(gsum, gcnt, Wfc, bfc, (float*)d_out, G);
}

// Round 8
// 446.467 us; speedup vs baseline: 3.2373x; 3.2373x over previous
//
#include <hip/hip_runtime.h>
#include <hip/hip_bf16.h>
#include <math.h>

// ---------------------------------------------------------------------------
// GCN pipeline v3: dst-sorted CSR + wave-per-node register aggregation.
//   1) bin edges by dst bucket (BN=512) with LDS-staged coalesced flush
//   2) per-bucket counting sort by local dst -> global CSR (bl2 = src rows),
//      fused with deg/dinv/y1 prep; nod[i] packs (offset | deg<<23)
//   3) layer kernels: ONE WAVE PER NODE, register accum + __shfl_xor reduce,
//      fused tiny GEMM + ReLU (+ mean-pool atomics in layer 2).
//   No float scatter atomics except mean-pool into 132KB L2-resident table.
// ---------------------------------------------------------------------------

#define TPB 256
#define BSH 9
#define BN 512             // destination nodes per bucket
#define NBMAX 512
#define EPT 16             // edges per thread in k_bin
#define CAPL 16            // staging slots per bucket per chunk
#define ROWM 0x3FFFF

__device__ __forceinline__ void atomAddF(float* p, float v) {
    unsafeAtomicAdd(p, v);   // hardware global_atomic_add_f32
}

// --- K0: cursor init: cur[b] = b*CAPB ---
__global__ void k_curinit(int* __restrict__ cur, int NB, int CAPB) {
    int t = threadIdx.x;
    for (int b = t; b < NB; b += TPB) cur[b] = b * CAPB;
}

// --- K1: LDS-staged binning. Each block owns one 4096-edge chunk. ---
__global__ void k_bin(const int* __restrict__ row, const int* __restrict__ col, int E,
                      int NB, int* __restrict__ cur, unsigned* __restrict__ blist) {
    __shared__ unsigned lh[NBMAX * CAPL];
    __shared__ int lcnt[NBMAX];
    __shared__ int gb[NBMAX];
    const int t = threadIdx.x;
    for (int j = t; j < NBMAX; j += TPB) lcnt[j] = 0;
    __syncthreads();
    const int base = blockIdx.x * (TPB * EPT);
#pragma unroll 4
    for (int j = 0; j < EPT; ++j) {
        int e = base + j * TPB + t;
        if (e < E) {
            int c = col[e];
            int b = c >> BSH;
            unsigned val = (unsigned)row[e] | ((unsigned)(c & (BN - 1)) << 18);
            int pos = atomicAdd(&lcnt[b], 1);
            if (pos < CAPL) lh[b * CAPL + pos] = val;
            else { int gp = atomicAdd(&cur[b], 1); blist[gp] = val; }  // rare spill
        }
    }
    __syncthreads();
    for (int b = t; b < NB; b += TPB) {
        int c = min(lcnt[b], CAPL);
        gb[b] = c ? atomicAdd(&cur[b], c) : 0;
    }
    __syncthreads();
    for (int slot = t; slot < NB * CAPL; slot += TPB) {
        int b = slot >> 4;               // CAPL = 16
        int p = slot & (CAPL - 1);
        if (p < min(lcnt[b], CAPL)) blist[gb[b] + p] = lh[slot];
    }
}

// --- K2: per-bucket counting sort by local dst -> CSR; fused deg/dinv/y1 prep.
//     nod[i] = (csr_offset) | (deg << 23);  bl2[] = source row indices. ---
__global__ void k_lcsort(const unsigned* __restrict__ bl, const int* __restrict__ bend,
                         int CAPB, const float* __restrict__ x,
                         unsigned* __restrict__ bl2, unsigned* __restrict__ nod,
                         float* __restrict__ dinv, float4* __restrict__ y1, int N) {
    __shared__ int hist[BN];
    __shared__ int pre[BN];
    __shared__ int scur[BN];
    __shared__ int s[TPB];
    const int t = threadIdx.x, b = blockIdx.x;
    for (int j = t; j < BN; j += TPB) hist[j] = 0;
    __syncthreads();
    const int lo = b * CAPB, hi = bend[b];
    for (int k = lo + t; k < hi; k += TPB)
        atomicAdd(&hist[bl[k] >> 18], 1);
    __syncthreads();
    // exclusive scan of 512 bins via 256 pair-partials (Hillis-Steele)
    const int t2 = t * 2;
    s[t] = hist[t2] + hist[t2 + 1];
    __syncthreads();
    for (int d = 1; d < TPB; d <<= 1) {
        int v = (t >= d) ? s[t - d] : 0;
        __syncthreads();
        s[t] += v;
        __syncthreads();
    }
    int base0 = (t == 0) ? 0 : s[t - 1];
    pre[t2] = base0;
    pre[t2 + 1] = base0 + hist[t2];
    scur[t2] = pre[t2];
    scur[t2 + 1] = pre[t2 + 1];
    // fused node prep (2 nodes per thread)
#pragma unroll
    for (int j = 0; j < 2; ++j) {
        int lcl = t2 + j;
        int i = b * BN + lcl;
        if (i < N) {
            int deg = hist[lcl];
            nod[i] = (unsigned)(lo + pre[lcl]) | ((unsigned)deg << 23);
            float d = rsqrtf(1.0f + (float)deg);
            dinv[i] = d;
            float4 v;
            v.x = x[3 * (size_t)i + 0] * d;
            v.y = x[3 * (size_t)i + 1] * d;
            v.z = x[3 * (size_t)i + 2] * d;
            v.w = 0.0f;
            y1[i] = v;
        }
    }
    __syncthreads();
    // scatter: dst-sorted within bucket => globally dst-sorted CSR
    for (int k = lo + t; k < hi; k += TPB) {
        unsigned pv = bl[k];
        int lc = pv >> 18;
        int pos = atomicAdd(&scur[lc], 1);
        bl2[lo + pos] = pv & ROWM;
    }
}

// --- K3: layer1, one wave per node: 64-lane gather + shfl reduce + 3x16 GEMM ---
__global__ void k_l1(const unsigned* __restrict__ bl2, const unsigned* __restrict__ nod,
                     const float4* __restrict__ y1, const float* __restrict__ dinv,
                     const float* __restrict__ W1, const float* __restrict__ b1,
                     float* __restrict__ y2, int N) {
    __shared__ float sW[48];
    __shared__ float sb[16];
    if (threadIdx.x < 48) sW[threadIdx.x] = W1[threadIdx.x];
    if (threadIdx.x < 16) sb[threadIdx.x] = b1[threadIdx.x];
    __syncthreads();
    const int lane = threadIdx.x & 63;
    const int i = blockIdx.x * 4 + (threadIdx.x >> 6);
    if (i >= N) return;
    const unsigned u = nod[i];
    const int s = u & 0x7FFFFF;
    const int e = s + (int)(u >> 23);
    float ax = 0.f, ay = 0.f, az = 0.f;
    for (int k = s + lane; k < e; k += 64) {
        float4 v = y1[bl2[k]];
        ax += v.x; ay += v.y; az += v.z;
    }
#pragma unroll
    for (int m = 1; m < 64; m <<= 1) {
        ax += __shfl_xor(ax, m);
        ay += __shfl_xor(ay, m);
        az += __shfl_xor(az, m);
    }
    float4 a = y1[i];                  // self-loop (pre-scaled)
    const float d = dinv[i];
    ax = (ax + a.x) * d; ay = (ay + a.y) * d; az = (az + a.z) * d;
    if (lane < 16) {
        float tv = sb[lane] + ax * sW[lane] + ay * sW[16 + lane] + az * sW[32 + lane];
        y2[(size_t)i * 16 + lane] = fmaxf(tv, 0.0f) * d;   // relu + prescale
    }
}

// --- K4: layer2, one wave per node: 16 edges/iter x 4 lanes x 16B,
//     shfl reduce + broadcast, 16x32 GEMM + relu + mean-pool atomics ---
__global__ void k_l2(const unsigned* __restrict__ bl2, const unsigned* __restrict__ nod,
                     const float* __restrict__ y2, const float* __restrict__ dinv,
                     const float* __restrict__ W2, const float* __restrict__ b2,
                     const int* __restrict__ batch,
                     float* __restrict__ gsum, float* __restrict__ gcnt, int N) {
    __shared__ float sW[512];
    __shared__ float sb[32];
    for (int j = threadIdx.x; j < 512; j += TPB) sW[j] = W2[j];
    if (threadIdx.x < 32) sb[threadIdx.x] = b2[threadIdx.x];
    __syncthreads();
    const int lane = threadIdx.x & 63;
    const int q = lane & 3, eo = lane >> 2;
    const int i = blockIdx.x * 4 + (threadIdx.x >> 6);
    if (i >= N) return;
    const unsigned u = nod[i];
    const int s = u & 0x7FFFFF;
    const int e = s + (int)(u >> 23);
    float4 acc = make_float4(0.f, 0.f, 0.f, 0.f);
    for (int k = s + eo; k < e; k += 16) {
        int r = bl2[k];                          // 4 lanes broadcast-read
        float4 v = *(const float4*)(y2 + (size_t)r * 16 + q * 4);
        acc.x += v.x; acc.y += v.y; acc.z += v.z; acc.w += v.w;
    }
#pragma unroll
    for (int m = 4; m < 64; m <<= 1) {
        acc.x += __shfl_xor(acc.x, m);
        acc.y += __shfl_xor(acc.y, m);
        acc.z += __shfl_xor(acc.z, m);
        acc.w += __shfl_xor(acc.w, m);
    }
    float4 sv = *(const float4*)(y2 + (size_t)i * 16 + q * 4);   // self
    const float d = dinv[i];
    acc.x = (acc.x + sv.x) * d; acc.y = (acc.y + sv.y) * d;
    acc.z = (acc.z + sv.z) * d; acc.w = (acc.w + sv.w) * d;
    float v[16];
#pragma unroll
    for (int j = 0; j < 4; ++j) {               // lane j holds quarter q=j
        v[4*j+0] = __shfl(acc.x, j);
        v[4*j+1] = __shfl(acc.y, j);
        v[4*j+2] = __shfl(acc.z, j);
        v[4*j+3] = __shfl(acc.w, j);
    }
    const int g = batch[i];
    if (lane < 32) {
        float tv = sb[lane];
#pragma unroll
        for (int c = 0; c < 16; ++c) tv += v[c] * sW[c * 32 + lane];
        atomAddF(&gsum[(size_t)g * 32 + lane], fmaxf(tv, 0.0f));
    }
    if (lane == 32) atomAddF(&gcnt[g], 1.0f);
}

// --- K5: mean -> FC -> log_softmax ---
__global__ void k_head(const float* __restrict__ gsum, const float* __restrict__ gcnt,
                       const float* __restrict__ Wfc, const float* __restrict__ bfc,
                       float* __restrict__ out, int G) {
    int g = blockIdx.x * TPB + threadIdx.x;
    if (g < G) {
        float inv = 1.0f / fmaxf(gcnt[g], 1.0f);
        float l0 = bfc[0], l1 = bfc[1];
        const float* gs = gsum + (size_t)g * 32;
#pragma unroll
        for (int j = 0; j < 32; ++j) {
            float m = gs[j] * inv;
            l0 += m * Wfc[j * 2 + 0];
            l1 += m * Wfc[j * 2 + 1];
        }
        float mx = fmaxf(l0, l1);
        float lse = mx + logf(expf(l0 - mx) + expf(l1 - mx));
        out[g * 2 + 0] = l0 - lse;
        out[g * 2 + 1] = l1 - lse;
    }
}

extern "C" void kernel_launch(void* const* d_in, const int* in_sizes, int n_in,
                              void* d_out, int out_size, void* d_ws, size_t ws_size,
                              hipStream_t stream) {
    const float* x     = (const float*)d_in[0];
    const int*   edge  = (const int*)  d_in[1];
    const int*   batch = (const int*)  d_in[2];
    const float* W1    = (const float*)d_in[3];
    const float* b1    = (const float*)d_in[4];
    const float* W2    = (const float*)d_in[5];
    const float* b2    = (const float*)d_in[6];
    const float* Wfc   = (const float*)d_in[7];
    const float* bfc   = (const float*)d_in[8];

    const int N = in_sizes[0] / 3;
    const int E = in_sizes[1] / 2;
    const int G = out_size / 2;
    const int NB = (N + BN - 1) >> BSH;              // 391 for N=200000
    const int CAPB = (E + NB - 1) / NB + 2048;       // mean + ~16 sigma slack
    const int* row = edge;
    const int* col = edge + E;

    // workspace partition (256B aligned)
    char* base = (char*)d_ws;
    size_t o = 0;
    auto take = [&](size_t bytes) { char* r = base + o; o += (bytes + 255) & ~(size_t)255; return r; };
    int*      cur    = (int*)     take((size_t)NB * 4);
    unsigned* blistA = (unsigned*)take((size_t)NB * CAPB * 4);
    unsigned* blistB = (unsigned*)take((size_t)NB * CAPB * 4);
    unsigned* nod    = (unsigned*)take((size_t)N * 4);
    float*    dinv   = (float*)   take((size_t)N * 4);
    float4*   y1     = (float4*)  take((size_t)N * 16);
    float*    y2     = (float*)   take((size_t)N * 64);
    float*    gsum   = (float*)   take((size_t)G * 33 * 4);
    float*    gcnt   = gsum + (size_t)G * 32;

    hipMemsetAsync(gsum, 0, (size_t)G * 33 * 4, stream);

    const int gBin = (E + TPB * EPT - 1) / (TPB * EPT);
    const int gW   = (N + 3) / 4;                    // wave-per-node kernels
    const int gG   = (G + TPB - 1) / TPB;

    k_curinit <<<1, TPB, 0, stream>>>(cur, NB, CAPB);
    k_bin     <<<gBin, TPB, 0, stream>>>(row, col, E, NB, cur, blistA);
    k_lcsort  <<<NB, TPB, 0, stream>>>(blistA, cur, CAPB, x, blistB, nod, dinv, y1, N);
    k_l1      <<<gW, TPB, 0, stream>>>(blistB, nod, y1, dinv, W1, b1, y2, N);
    k_l2      <<<gW, TPB, 0, stream>>>(blistB, nod, y2, dinv, W2, b2, batch, gsum, gcnt, N);
    k_head    <<<gG, TPB, 0, stream>>>(gsum, gcnt, Wfc, bfc, (float*)d_out, G);
}